// Round 3
// baseline (465.724 us; speedup 1.0000x reference)
//
#include <hip/hip_runtime.h>

typedef unsigned short u16;
typedef short short8 __attribute__((ext_vector_type(8)));
typedef float f32x4 __attribute__((ext_vector_type(4)));

#define NB   512
#define NPG  211
#define NOBJ 10
#define NVAL 200
#define NE   420
#define NN   (NB * NPG)

__device__ __forceinline__ float bf2f(u16 u){
  union { unsigned i; float f; } v; v.i = ((unsigned)u) << 16; return v.f;
}
__device__ __forceinline__ u16 f2bf(float f){
  union { float f; unsigned i; } v; v.f = f;
  return (u16)((v.i + 0x7FFFu + ((v.i >> 16) & 1u)) >> 16);
}
__device__ __forceinline__ float lrelu(float s){ return s > 0.f ? s : 0.2f * s; }
__device__ __forceinline__ short8 pack8(ushort4 a, ushort4 b){
  short8 v;
  v[0]=(short)a.x; v[1]=(short)a.y; v[2]=(short)a.z; v[3]=(short)a.w;
  v[4]=(short)b.x; v[5]=(short)b.y; v[6]=(short)b.z; v[7]=(short)b.w;
  return v;
}
// XOR swizzle inside a [*][128] u16 LDS tile, 4-element chunk granularity.
__device__ __forceinline__ int swz(int r, int c){
  return (r << 7) + (((c & ~3) ^ ((r & 15) << 2)) | (c & 3));
}

// ---------------- prep: transposed weights, f32 -> bf16 (ws) ----------------
__global__ __launch_bounds__(256) void k_prept(const float* __restrict__ W1, const float* __restrict__ W2,
                                               u16* __restrict__ W1t, u16* __restrict__ W2t){
  int gid = blockIdx.x * 256 + threadIdx.x;      // 320 blocks -> 81920
  if (gid < 16384){
    int k = gid >> 7, n = gid & 127;
    W1t[n * 128 + k] = f2bf(W1[k * 128 + n]);    // W1t[n][k] = W1[k][n]
  } else {
    int t = gid - 16384;                          // 0..65535
    int n = t >> 9, kk = t & 511;
    int h = kk >> 7, c = kk & 127;
    W2t[n * 512 + kk] = f2bf(W2[c * 512 + h * 128 + n]); // W2t[n][h*128+k] = W2[k][h*128+n]
  }
}

// ---------------- prep: layer-2 attention vectors (ws, f32) ----------------
__global__ __launch_bounds__(256) void k_prepwm(const float* __restrict__ W2, const float* __restrict__ as2,
                                                const float* __restrict__ ad2,
                                                float* __restrict__ wms, float* __restrict__ wmd){
  int gid = blockIdx.x * 256 + threadIdx.x;      // 4 blocks -> 1024
  int which = gid >> 9, hk = gid & 511;
  int h = hk >> 7, k = hk & 127;
  const float* av = which ? ad2 : as2;
  float s = 0.f;
  for (int j = 0; j < 128; ++j)
    s += W2[k * 512 + h * 128 + j] * av[h * 128 + j];
  (which ? wmd : wms)[hk] = s;
}

// ---------------- fully fused per-graph kernel ----------------
// LDS map (bytes):
//   sX   @      0 : u16 [211][128] swizzled  (x -> x1 -> out2)
//   sY   @  54016 : u16 [211][128] swizzled  (xs1 -> y_h)
//   sA1s @ 108032 : f32 [211][4]   (att logits)
//   sA1d @ 111408 : f32 [211][4]
//   sA2s @ 114784 : f32 [211][4]
//   sA2d @ 118160 : f32 [211][4]
//   sEs  @ 121536 : i32 [420]
//   sEd  @ 123216 : i32 [420]
//   sOff @ 124896 : i32 [212]
//   sSrc @ 125744 : i32 [631]     end 128268
__global__ __launch_bounds__(512, 2) void k_graph(
    const float* __restrict__ head, const float* __restrict__ obj, const float* __restrict__ val,
    const int* __restrict__ eidx, const float* __restrict__ amask,
    const float* __restrict__ Wh, const float* __restrict__ bh,
    const float* __restrict__ Wo, const float* __restrict__ bo,
    const float* __restrict__ Wv, const float* __restrict__ bv,
    const u16* __restrict__ W1t, const float* __restrict__ as1, const float* __restrict__ ad1,
    const float* __restrict__ b1,
    const u16* __restrict__ W2t, const float* __restrict__ wms, const float* __restrict__ wmd,
    const float* __restrict__ b2,
    const float* __restrict__ Wacc, const float* __restrict__ bacc,
    const float* __restrict__ Woff, const float* __restrict__ boff,
    const float* __restrict__ Wvf,  const float* __restrict__ bvf,
    float* __restrict__ out)
{
  __shared__ __align__(16) char sm[128272];
  u16*   sX   = (u16*)sm;
  u16*   sY   = (u16*)(sm + 54016);
  float* sA1s = (float*)(sm + 108032);
  float* sA1d = (float*)(sm + 111408);
  float* sA2s = (float*)(sm + 114784);
  float* sA2d = (float*)(sm + 118160);
  int*   sEs  = (int*)(sm + 121536);
  int*   sEd  = (int*)(sm + 123216);
  int*   sOff = (int*)(sm + 124896);
  int*   sSrc = (int*)(sm + 125744);

  const int b    = blockIdx.x;
  const int tid  = threadIdx.x;
  const int lane = tid & 63;
  const int wv   = tid >> 6;
  const int l15  = lane & 15;
  const int lg   = lane >> 4;
  const int rtb  = (wv >> 2) * 7;      // row-tile base (0 or 7); 14 tiles cover 224 rows
  const int cb   = (wv & 3) * 32;      // col base; 2 col-tiles per wave

  // ---- P0: stage edge list ----
  const int* eg = eidx + (size_t)b * 2 * NE;
  for (int i = tid; i < NE; i += 512){ sEs[i] = eg[i]; sEd[i] = eg[NE + i]; }

  // ---- P1: embed -> sX (bf16) ----
  for (int it = tid; it < NPG * 32; it += 512){
    int n = it >> 5, c0 = (it & 31) << 2;
    float a[4];
    if (n == 0){
      const float* in = head + (size_t)b * 2;
      float i0 = in[0], i1 = in[1];
      #pragma unroll
      for (int t = 0; t < 4; ++t){ int c = c0 + t; a[t] = bh[c] + i0 * Wh[c] + i1 * Wh[128 + c]; }
    } else if (n <= NOBJ){
      const float* in = obj + ((size_t)b * NOBJ + (n - 1)) * 2;
      float i0 = in[0], i1 = in[1];
      #pragma unroll
      for (int t = 0; t < 4; ++t){ int c = c0 + t; a[t] = bo[c] + i0 * Wo[c] + i1 * Wo[128 + c]; }
    } else {
      const float* in = val + ((size_t)b * NVAL + (n - 11)) * 5;
      float f[5];
      #pragma unroll
      for (int k = 0; k < 5; ++k) f[k] = in[k];
      #pragma unroll
      for (int t = 0; t < 4; ++t){
        int c = c0 + t; float s = bv[c];
        #pragma unroll
        for (int k = 0; k < 5; ++k) s += f[k] * Wv[k * 128 + c];
        a[t] = s;
      }
    }
    ushort4 u;
    u.x = f2bf(fmaxf(a[0], 0.f)); u.y = f2bf(fmaxf(a[1], 0.f));
    u.z = f2bf(fmaxf(a[2], 0.f)); u.w = f2bf(fmaxf(a[3], 0.f));
    *(ushort4*)&sX[swz(n, c0)] = u;
  }
  __syncthreads();

  // ---- P2: CSR degrees -> exclusive scan -> fill ----
  if (tid < NPG){
    int c = 1;                                    // self loop
    for (int i = 0; i < NE; ++i) c += (sEd[i] == tid);
    sOff[tid] = c;
  }
  __syncthreads();
  if (tid == 0){
    int s = 0;
    for (int l = 0; l < NPG; ++l){ int t = sOff[l]; sOff[l] = s; s += t; }
    sOff[NPG] = s;
  }
  __syncthreads();
  if (tid < NPG){
    int p = sOff[tid];
    sSrc[p++] = tid;                              // self loop first
    for (int i = 0; i < NE; ++i) if (sEd[i] == tid) sSrc[p++] = sEs[i];
  }
  __syncthreads();

  // ---- P4: gemm1  xs1 = x @ W1  -> sY (bf16) ----
  f32x4 acc[7][2];
  #pragma unroll
  for (int i = 0; i < 7; ++i){ acc[i][0] = (f32x4){0,0,0,0}; acc[i][1] = (f32x4){0,0,0,0}; }
  #pragma unroll
  for (int kk = 0; kk < 4; ++kk){
    int k0 = kk * 32 + (lg << 2);
    const u16* B0 = W1t + (size_t)(cb + l15) * 128 + k0;
    const u16* B1 = W1t + (size_t)(cb + 16 + l15) * 128 + k0;
    short8 bf0 = pack8(*(const ushort4*)B0, *(const ushort4*)(B0 + 16));
    short8 bf1 = pack8(*(const ushort4*)B1, *(const ushort4*)(B1 + 16));
    #pragma unroll
    for (int mi = 0; mi < 7; ++mi){
      int rr = (rtb + mi) * 16 + l15; rr = rr < NPG ? rr : NPG - 1;   // row clamp
      short8 af = pack8(*(const ushort4*)&sX[swz(rr, k0)],
                        *(const ushort4*)&sX[swz(rr, k0 + 16)]);
      acc[mi][0] = __builtin_amdgcn_mfma_f32_16x16x32_bf16(af, bf0, acc[mi][0], 0, 0, 0);
      acc[mi][1] = __builtin_amdgcn_mfma_f32_16x16x32_bf16(af, bf1, acc[mi][1], 0, 0, 0);
    }
  }
  #pragma unroll
  for (int mi = 0; mi < 7; ++mi){
    int r0 = (rtb + mi) * 16 + (lg << 2);
    #pragma unroll
    for (int ct = 0; ct < 2; ++ct){
      int col = cb + ct * 16 + l15;
      #pragma unroll
      for (int r = 0; r < 4; ++r){
        int row = r0 + r;
        if (row < NPG) sY[swz(row, col)] = f2bf(acc[mi][ct][r]);
      }
    }
  }
  __syncthreads();

  // ---- P5: att1 logits from xs1 ----
  for (int p = tid; p < NPG * 4; p += 512){
    int n = p >> 2, h = p & 3;
    float s = 0.f, d = 0.f;
    #pragma unroll
    for (int j = 0; j < 8; ++j){
      int c = h * 32 + j * 4;
      ushort4 xv = *(const ushort4*)&sY[swz(n, c)];
      #pragma unroll
      for (int t = 0; t < 4; ++t){
        float xf = bf2f(((const u16*)&xv)[t]);
        s += xf * as1[c + t];
        d += xf * ad1[c + t];
      }
    }
    sA1s[p] = s; sA1d[p] = d;
  }
  __syncthreads();

  // ---- P6: gat1 -> x1 into sX ----
  {
    const int c0 = lane, c1 = lane + 64;
    const int hse = lane >> 5;                 // c0 head = hse, c1 head = 2+hse
    const float b1v0 = b1[c0], b1v1 = b1[c1];
    for (int dst = wv; dst < NPG; dst += 8){
      int o0 = sOff[dst], o1 = sOff[dst + 1];
      float d0 = sA1d[dst*4], d1 = sA1d[dst*4+1], d2 = sA1d[dst*4+2], d3 = sA1d[dst*4+3];
      float m0 = -3e38f, m1 = -3e38f, m2 = -3e38f, m3 = -3e38f;
      for (int e = o0; e < o1; ++e){
        int s4 = sSrc[e] * 4;
        m0 = fmaxf(m0, lrelu(sA1s[s4]   + d0));
        m1 = fmaxf(m1, lrelu(sA1s[s4+1] + d1));
        m2 = fmaxf(m2, lrelu(sA1s[s4+2] + d2));
        m3 = fmaxf(m3, lrelu(sA1s[s4+3] + d3));
      }
      float dn0 = 0, dn1 = 0, dn2 = 0, dn3 = 0, a0 = 0, a1 = 0;
      for (int e = o0; e < o1; ++e){
        int sn = sSrc[e]; int s4 = sn * 4;
        float e0 = __expf(lrelu(sA1s[s4]   + d0) - m0);
        float e1 = __expf(lrelu(sA1s[s4+1] + d1) - m1);
        float e2 = __expf(lrelu(sA1s[s4+2] + d2) - m2);
        float e3 = __expf(lrelu(sA1s[s4+3] + d3) - m3);
        dn0 += e0; dn1 += e1; dn2 += e2; dn3 += e3;
        a0 += (hse ? e1 : e0) * bf2f(sY[swz(sn, c0)]);
        a1 += (hse ? e3 : e2) * bf2f(sY[swz(sn, c1)]);
      }
      float dA = hse ? dn1 : dn0;
      float dB = hse ? dn3 : dn2;
      sX[swz(dst, c0)] = f2bf(fmaxf(a0 / (dA + 1e-16f) + b1v0, 0.f));
      sX[swz(dst, c1)] = f2bf(fmaxf(a1 / (dB + 1e-16f) + b1v1, 0.f));
    }
  }
  __syncthreads();

  // ---- P7: att2 logits from x1 (wms/wmd = W2_h @ att2_h, precomputed) ----
  for (int p = tid; p < NPG * 4; p += 512){
    int n = p >> 2, h = p & 3;
    const float* ws = wms + h * 128;
    const float* wd = wmd + h * 128;
    float s = 0.f, d = 0.f;
    #pragma unroll
    for (int j = 0; j < 32; ++j){
      ushort4 xv = *(const ushort4*)&sX[swz(n, j * 4)];
      #pragma unroll
      for (int t = 0; t < 4; ++t){
        float xf = bf2f(((const u16*)&xv)[t]);
        s += xf * ws[j * 4 + t];
        d += xf * wd[j * 4 + t];
      }
    }
    sA2s[p] = s; sA2d[p] = d;
  }
  __syncthreads();

  // ---- P8: per head: build y_h -> sY, MFMA accumulate out2 ----
  #pragma unroll
  for (int i = 0; i < 7; ++i){ acc[i][0] = (f32x4){0,0,0,0}; acc[i][1] = (f32x4){0,0,0,0}; }
  for (int h = 0; h < 4; ++h){
    {
      const int c0 = lane, c1 = lane + 64;
      for (int dst = wv; dst < NPG; dst += 8){
        int o0 = sOff[dst], o1 = sOff[dst + 1];
        float adh = sA2d[dst * 4 + h];
        float mx = -3e38f;
        for (int e = o0; e < o1; ++e)
          mx = fmaxf(mx, lrelu(sA2s[sSrc[e] * 4 + h] + adh));
        float dn = 0.f, a0 = 0.f, a1 = 0.f;
        for (int e = o0; e < o1; ++e){
          int sn = sSrc[e];
          float ee = __expf(lrelu(sA2s[sn * 4 + h] + adh) - mx);
          dn += ee;
          a0 += ee * bf2f(sX[swz(sn, c0)]);
          a1 += ee * bf2f(sX[swz(sn, c1)]);
        }
        float w = 0.25f / (dn + 1e-16f);
        sY[swz(dst, c0)] = f2bf(a0 * w);
        sY[swz(dst, c1)] = f2bf(a1 * w);
      }
    }
    __syncthreads();
    #pragma unroll
    for (int kk = 0; kk < 4; ++kk){
      int k0 = kk * 32 + (lg << 2);
      const u16* B0 = W2t + (size_t)(cb + l15) * 512 + h * 128 + k0;
      const u16* B1 = W2t + (size_t)(cb + 16 + l15) * 512 + h * 128 + k0;
      short8 bf0 = pack8(*(const ushort4*)B0, *(const ushort4*)(B0 + 16));
      short8 bf1 = pack8(*(const ushort4*)B1, *(const ushort4*)(B1 + 16));
      #pragma unroll
      for (int mi = 0; mi < 7; ++mi){
        int rr = (rtb + mi) * 16 + l15; rr = rr < NPG ? rr : NPG - 1;
        short8 af = pack8(*(const ushort4*)&sY[swz(rr, k0)],
                          *(const ushort4*)&sY[swz(rr, k0 + 16)]);
        acc[mi][0] = __builtin_amdgcn_mfma_f32_16x16x32_bf16(af, bf0, acc[mi][0], 0, 0, 0);
        acc[mi][1] = __builtin_amdgcn_mfma_f32_16x16x32_bf16(af, bf1, acc[mi][1], 0, 0, 0);
      }
    }
    __syncthreads();
  }

  // ---- P9: out2 = relu(acc + b2) -> sX (bf16) ----
  #pragma unroll
  for (int mi = 0; mi < 7; ++mi){
    int r0 = (rtb + mi) * 16 + (lg << 2);
    #pragma unroll
    for (int ct = 0; ct < 2; ++ct){
      int col = cb + ct * 16 + l15;
      float bv = b2[col];
      #pragma unroll
      for (int r = 0; r < 4; ++r){
        int row = r0 + r;
        if (row < NPG) sX[swz(row, col)] = f2bf(fmaxf(acc[mi][ct][r] + bv, 0.f));
      }
    }
  }
  __syncthreads();

  // ---- P10: final projections -> out (f32) ----
  if (tid < 203){
    float s; int pos;
    if (tid < 200){
      int row = 11 + tid;
      s = boff[0];
      #pragma unroll
      for (int j = 0; j < 32; ++j){
        ushort4 xv = *(const ushort4*)&sX[swz(row, j * 4)];
        #pragma unroll
        for (int t = 0; t < 4; ++t) s += bf2f(((const u16*)&xv)[t]) * Woff[j * 4 + t];
      }
      pos = 2 + tid;
    } else if (tid < 202){
      int j2 = tid - 200;
      s = bacc[j2];
      #pragma unroll
      for (int j = 0; j < 32; ++j){
        ushort4 xv = *(const ushort4*)&sX[swz(0, j * 4)];
        #pragma unroll
        for (int t = 0; t < 4; ++t) s += bf2f(((const u16*)&xv)[t]) * Wacc[(j * 4 + t) * 2 + j2];
      }
      float lm = logf(amask[b * 2 + j2]);
      s += fmaxf(lm, -3.402823466e38f);
      pos = j2;
    } else {
      s = bvf[0];
      #pragma unroll
      for (int j = 0; j < 32; ++j){
        ushort4 xv = *(const ushort4*)&sX[swz(0, j * 4)];
        #pragma unroll
        for (int t = 0; t < 4; ++t) s += bf2f(((const u16*)&xv)[t]) * Wvf[j * 4 + t];
      }
      pos = 202;
    }
    out[(size_t)b * 203 + pos] = s;
  }
}

extern "C" void kernel_launch(void* const* d_in, const int* in_sizes, int n_in,
                              void* d_out, int out_size, void* d_ws, size_t ws_size,
                              hipStream_t stream){
  (void)in_sizes; (void)n_in; (void)out_size; (void)ws_size;
  const float* head = (const float*)d_in[0];
  const float* obj  = (const float*)d_in[1];
  const float* val  = (const float*)d_in[2];
  const int*   eidx = (const int*)d_in[3];
  const float* amask= (const float*)d_in[4];
  const float* Wh   = (const float*)d_in[5];
  const float* bh   = (const float*)d_in[6];
  const float* Wo   = (const float*)d_in[7];
  const float* bo   = (const float*)d_in[8];
  const float* Wv   = (const float*)d_in[9];
  const float* bv   = (const float*)d_in[10];
  const float* W1   = (const float*)d_in[11];
  const float* as1  = (const float*)d_in[12];
  const float* ad1  = (const float*)d_in[13];
  const float* b1   = (const float*)d_in[14];
  const float* W2   = (const float*)d_in[15];
  const float* as2  = (const float*)d_in[16];
  const float* ad2  = (const float*)d_in[17];
  const float* b2   = (const float*)d_in[18];
  const float* Wacc = (const float*)d_in[19];
  const float* bacc = (const float*)d_in[20];
  const float* Woff = (const float*)d_in[21];
  const float* boff = (const float*)d_in[22];
  const float* Wvf  = (const float*)d_in[23];
  const float* bvf  = (const float*)d_in[24];
  float* out = (float*)d_out;

  char* ws = (char*)d_ws;
  u16*   W1t = (u16*)ws;                    //  32768 B
  u16*   W2t = (u16*)(ws + 32768);          // 131072 B
  float* wms = (float*)(ws + 163840);       //   2048 B
  float* wmd = (float*)(ws + 165888);       //   2048 B  (total ws: 168 KB)

  k_prept<<<320, 256, 0, stream>>>(W1, W2, W1t, W2t);
  k_prepwm<<<4, 256, 0, stream>>>(W2, as2, ad2, wms, wmd);
  k_graph<<<NB, 512, 0, stream>>>(head, obj, val, eidx, amask,
                                  Wh, bh, Wo, bo, Wv, bv,
                                  W1t, as1, ad1, b1,
                                  W2t, wms, wmd, b2,
                                  Wacc, bacc, Woff, boff, Wvf, bvf, out);
}

// Round 5
// 279.345 us; speedup vs baseline: 1.6672x; 1.6672x over previous
//
#include <hip/hip_runtime.h>

typedef unsigned short u16;
typedef short short8 __attribute__((ext_vector_type(8)));
typedef float f32x4 __attribute__((ext_vector_type(4)));

#define NB   512
#define NPG  211
#define NOBJ 10
#define NVAL 200
#define NE   420
#define NN   (NB * NPG)

__device__ __forceinline__ float bf2f(u16 u){
  union { unsigned i; float f; } v; v.i = ((unsigned)u) << 16; return v.f;
}
__device__ __forceinline__ u16 f2bf(float f){
  union { float f; unsigned i; } v; v.f = f;
  return (u16)((v.i + 0x7FFFu + ((v.i >> 16) & 1u)) >> 16);
}
__device__ __forceinline__ float lrelu(float s){ return s > 0.f ? s : 0.2f * s; }
__device__ __forceinline__ short8 pack8(ushort4 a, ushort4 b){
  short8 v;
  v[0]=(short)a.x; v[1]=(short)a.y; v[2]=(short)a.z; v[3]=(short)a.w;
  v[4]=(short)b.x; v[5]=(short)b.y; v[6]=(short)b.z; v[7]=(short)b.w;
  return v;
}
// XOR swizzle inside a [*][128] u16 LDS tile, 4-element chunk granularity.
__device__ __forceinline__ int swz(int r, int c){
  return (r << 7) + (((c & ~3) ^ ((r & 15) << 2)) | (c & 3));
}

// ---------------- prep: transposed weights, f32 -> bf16 (ws) ----------------
__global__ __launch_bounds__(256) void k_prept(const float* __restrict__ W1, const float* __restrict__ W2,
                                               u16* __restrict__ W1t, u16* __restrict__ W2t){
  int gid = blockIdx.x * 256 + threadIdx.x;      // 320 blocks -> 81920
  if (gid < 16384){
    int k = gid >> 7, n = gid & 127;
    W1t[n * 128 + k] = f2bf(W1[k * 128 + n]);
  } else {
    int t = gid - 16384;
    int n = t >> 9, kk = t & 511;
    int h = kk >> 7, c = kk & 127;
    W2t[n * 512 + kk] = f2bf(W2[c * 512 + h * 128 + n]);
  }
}

// ---------------- prep: layer-2 attention vectors (ws, f32) ----------------
__global__ __launch_bounds__(256) void k_prepwm(const float* __restrict__ W2, const float* __restrict__ as2,
                                                const float* __restrict__ ad2,
                                                float* __restrict__ wms, float* __restrict__ wmd){
  int gid = blockIdx.x * 256 + threadIdx.x;      // 4 blocks -> 1024
  int which = gid >> 9, hk = gid & 511;
  int h = hk >> 7, k = hk & 127;
  const float* av = which ? ad2 : as2;
  float s = 0.f;
  for (int j = 0; j < 128; ++j)
    s += W2[k * 512 + h * 128 + j] * av[h * 128 + j];
  (which ? wmd : wms)[hk] = s;
}

// ---------------- fully fused per-graph kernel (1024 threads) ----------------
// LDS map (bytes):
//   sX   @      0 : u16 [211][128] swz   (x -> x1 -> out2)
//   sY   @  54016 : u16 [211][128] swz   (xs1 -> y_h)
//   sLs  @ 108032 : f32 [844]  (att src-logits, reused L1 then L2)
//   sLd  @ 111408 : f32 [844]  (att dst-logits)
//   sW   @ 114784 : f32 [2528] (per-slot softmax weights [4][632]; also wm staging)
//   sDen @ 124896 : f32 [844]  (recip denominators [4][211]; also as1/ad1 staging)
//   sEs  @ 128272 : i32 [420]
//   sEd  @ 129952 : i32 [420]
//   sOff @ 131632 : i32 [212]
//   sSrc @ 132480 : i32 [631]  (also scan temp)      end 135004
__global__ __launch_bounds__(1024, 1) void k_graph(
    const float* __restrict__ head, const float* __restrict__ obj, const float* __restrict__ val,
    const int* __restrict__ eidx, const float* __restrict__ amask,
    const float* __restrict__ Wh, const float* __restrict__ bh,
    const float* __restrict__ Wo, const float* __restrict__ bo,
    const float* __restrict__ Wv, const float* __restrict__ bv,
    const u16* __restrict__ W1t, const float* __restrict__ as1, const float* __restrict__ ad1,
    const float* __restrict__ b1,
    const u16* __restrict__ W2t, const float* __restrict__ wms, const float* __restrict__ wmd,
    const float* __restrict__ b2,
    const float* __restrict__ Wacc, const float* __restrict__ bacc,
    const float* __restrict__ Woff, const float* __restrict__ boff,
    const float* __restrict__ Wvf,  const float* __restrict__ bvf,
    float* __restrict__ out)
{
  __shared__ __align__(16) char sm[135008];
  u16*   sX   = (u16*)sm;
  u16*   sY   = (u16*)(sm + 54016);
  float* sLs  = (float*)(sm + 108032);
  float* sLd  = (float*)(sm + 111408);
  float* sW   = (float*)(sm + 114784);
  float* sDen = (float*)(sm + 124896);
  int*   sEs  = (int*)(sm + 128272);
  int*   sEd  = (int*)(sm + 129952);
  int*   sOff = (int*)(sm + 131632);
  int*   sSrc = (int*)(sm + 132480);

  const int b    = blockIdx.x;
  const int tid  = threadIdx.x;
  const int lane = tid & 63;
  const int wv   = tid >> 6;          // 16 waves
  const int l15  = lane & 15;
  const int lg   = lane >> 4;
  const int c0   = lane, c1 = lane + 64;
  const int hse  = lane >> 5;         // c0 head = hse, c1 head = 2+hse

  // MFMA tile assignment: 14 row-tiles(16) x 4 col-pairs(32) = 56 tiles, round-robin over 16 waves
  int tmi[4], tcb[4]; bool tact[4];
  #pragma unroll
  for (int s = 0; s < 4; ++s){
    int t = wv + (s << 4);
    tact[s] = t < 56; tmi[s] = t >> 2; tcb[s] = (t & 3) << 5;
  }

  // ---- P0: stage edges + att1 vectors ----
  const int* eg = eidx + (size_t)b * 2 * NE;
  if (tid < NE){ sEs[tid] = eg[tid]; sEd[tid] = eg[NE + tid]; }
  else if (tid >= 512 && tid < 640)      sDen[tid - 512] = as1[tid - 512];   // as1 -> sDen[0..127]
  else if (tid >= 640 && tid < 768)      sDen[tid - 512] = ad1[tid - 640];   // ad1 -> sDen[128..255]

  // ---- P1: embed -> sX (bf16) ----
  for (int it = tid; it < NPG * 32; it += 1024){
    int n = it >> 5, cc = (it & 31) << 2;
    float a[4];
    if (n == 0){
      const float* in = head + (size_t)b * 2;
      float i0 = in[0], i1 = in[1];
      #pragma unroll
      for (int t = 0; t < 4; ++t){ int c = cc + t; a[t] = bh[c] + i0 * Wh[c] + i1 * Wh[128 + c]; }
    } else if (n <= NOBJ){
      const float* in = obj + ((size_t)b * NOBJ + (n - 1)) * 2;
      float i0 = in[0], i1 = in[1];
      #pragma unroll
      for (int t = 0; t < 4; ++t){ int c = cc + t; a[t] = bo[c] + i0 * Wo[c] + i1 * Wo[128 + c]; }
    } else {
      const float* in = val + ((size_t)b * NVAL + (n - 11)) * 5;
      float f[5];
      #pragma unroll
      for (int k = 0; k < 5; ++k) f[k] = in[k];
      #pragma unroll
      for (int t = 0; t < 4; ++t){
        int c = cc + t; float s = bv[c];
        #pragma unroll
        for (int k = 0; k < 5; ++k) s += f[k] * Wv[k * 128 + c];
        a[t] = s;
      }
    }
    ushort4 u;
    u.x = f2bf(fmaxf(a[0], 0.f)); u.y = f2bf(fmaxf(a[1], 0.f));
    u.z = f2bf(fmaxf(a[2], 0.f)); u.w = f2bf(fmaxf(a[3], 0.f));
    *(ushort4*)&sX[swz(n, cc)] = u;
  }
  __syncthreads();

  // ---- P2a: degrees ----
  if (tid < NPG){
    int c = 1;
    for (int i = 0; i < NE; ++i) c += (sEd[i] == tid);
    sOff[tid] = c;
  }
  __syncthreads();
  // ---- P2b: Hillis-Steele exclusive scan (256 lanes, sSrc as temp) ----
  {
    int deg = (tid < NPG) ? sOff[tid] : 0;
    int v = deg;
    #pragma unroll
    for (int st = 1; st < 256; st <<= 1){
      if (tid < 256) sSrc[tid] = v;
      __syncthreads();
      if (tid < 256 && tid >= st) v += sSrc[tid - st];
      __syncthreads();
    }
    if (tid < NPG) sOff[tid] = v - deg;
    if (tid == NPG - 1) sOff[NPG] = v;
  }
  __syncthreads();
  // ---- P2c: deterministic CSR fill ----
  if (tid < NPG){
    int p = sOff[tid];
    sSrc[p++] = tid;                              // self loop first
    for (int i = 0; i < NE; ++i) if (sEd[i] == tid) sSrc[p++] = sEs[i];
  }
  __syncthreads();

  // ---- P4: gemm1  xs1 = x @ W1 -> sY ----
  {
    f32x4 acc[4][2];
    #pragma unroll
    for (int s = 0; s < 4; ++s){ acc[s][0] = (f32x4){0,0,0,0}; acc[s][1] = (f32x4){0,0,0,0}; }
    #pragma unroll
    for (int kk = 0; kk < 4; ++kk){
      int k0 = kk * 32 + (lg << 2);
      #pragma unroll
      for (int s = 0; s < 4; ++s) if (tact[s]){
        const u16* B0 = W1t + (size_t)(tcb[s] + l15) * 128 + k0;
        const u16* B1 = W1t + (size_t)(tcb[s] + 16 + l15) * 128 + k0;
        short8 bf0 = pack8(*(const ushort4*)B0, *(const ushort4*)(B0 + 16));
        short8 bf1 = pack8(*(const ushort4*)B1, *(const ushort4*)(B1 + 16));
        int rr = tmi[s] * 16 + l15; rr = rr < NPG ? rr : NPG - 1;
        short8 af = pack8(*(const ushort4*)&sX[swz(rr, k0)],
                          *(const ushort4*)&sX[swz(rr, k0 + 16)]);
        acc[s][0] = __builtin_amdgcn_mfma_f32_16x16x32_bf16(af, bf0, acc[s][0], 0, 0, 0);
        acc[s][1] = __builtin_amdgcn_mfma_f32_16x16x32_bf16(af, bf1, acc[s][1], 0, 0, 0);
      }
    }
    #pragma unroll
    for (int s = 0; s < 4; ++s) if (tact[s]){
      int r0 = tmi[s] * 16 + (lg << 2);
      #pragma unroll
      for (int ct = 0; ct < 2; ++ct){
        int col = tcb[s] + ct * 16 + l15;
        #pragma unroll
        for (int r = 0; r < 4; ++r){
          int row = r0 + r;
          if (row < NPG) sY[swz(row, col)] = f2bf(acc[s][ct][r]);
        }
      }
    }
  }
  __syncthreads();

  // ---- P5: att1 logits (att vectors staged in sDen[0..255]) ----
  if (tid < NPG * 4){
    int n = tid >> 2, h = tid & 3;
    float s = 0.f, d = 0.f;
    #pragma unroll
    for (int j = 0; j < 8; ++j){
      int c = h * 32 + j * 4;
      ushort4 xv = *(const ushort4*)&sY[swz(n, c)];
      #pragma unroll
      for (int t = 0; t < 4; ++t){
        float xf = bf2f(((const u16*)&xv)[t]);
        s += xf * sDen[c + t];
        d += xf * sDen[128 + c + t];
      }
    }
    sLs[tid] = s; sLd[tid] = d;
  }
  __syncthreads();

  // ---- P5b: layer-1 per-slot softmax weights ----
  if (tid < NPG * 4){
    int dst = tid >> 2, h = tid & 3;
    int o0 = sOff[dst], o1 = sOff[dst + 1];
    float ad = sLd[tid];
    float m = -3e38f;
    for (int e = o0; e < o1; ++e) m = fmaxf(m, lrelu(sLs[sSrc[e] * 4 + h] + ad));
    float dn = 0.f;
    for (int e = o0; e < o1; ++e){
      float ee = __expf(lrelu(sLs[sSrc[e] * 4 + h] + ad) - m);
      sW[h * 632 + e] = ee; dn += ee;
    }
    sDen[h * 211 + dst] = 1.0f / (dn + 1e-16f);
  }
  __syncthreads();

  // ---- P6: gat1 aggregation -> x1 into sX ----
  {
    const float b1v0 = b1[c0], b1v1 = b1[c1];
    const float* w0p = sW + hse * 632;
    const float* w1p = sW + (2 + hse) * 632;
    for (int dst = wv; dst < NPG; dst += 16){
      int o0 = sOff[dst], o1 = sOff[dst + 1];
      float a0 = 0.f, a1 = 0.f;
      for (int e = o0; e < o1; ++e){
        int sn = sSrc[e];
        a0 += w0p[e] * bf2f(sY[swz(sn, c0)]);
        a1 += w1p[e] * bf2f(sY[swz(sn, c1)]);
      }
      float r0 = sDen[hse * 211 + dst], r1 = sDen[(2 + hse) * 211 + dst];
      sX[swz(dst, c0)] = f2bf(fmaxf(a0 * r0 + b1v0, 0.f));
      sX[swz(dst, c1)] = f2bf(fmaxf(a1 * r1 + b1v1, 0.f));
    }
  }
  __syncthreads();

  // ---- P7a: stage wms/wmd into sW[0..1023] ----
  sW[tid] = (tid < 512) ? wms[tid] : wmd[tid - 512];
  __syncthreads();

  // ---- P7: att2 logits from x1 ----
  if (tid < NPG * 4){
    int n = tid >> 2, h = tid & 3;
    const float* wsp = sW + h * 128;
    const float* wdp = sW + 512 + h * 128;
    float s = 0.f, d = 0.f;
    #pragma unroll
    for (int j = 0; j < 32; ++j){
      ushort4 xv = *(const ushort4*)&sX[swz(n, j * 4)];
      #pragma unroll
      for (int t = 0; t < 4; ++t){
        float xf = bf2f(((const u16*)&xv)[t]);
        s += xf * wsp[j * 4 + t];
        d += xf * wdp[j * 4 + t];
      }
    }
    sLs[tid] = s; sLd[tid] = d;
  }
  __syncthreads();

  // ---- P7b: layer-2 per-slot softmax weights ----
  if (tid < NPG * 4){
    int dst = tid >> 2, h = tid & 3;
    int o0 = sOff[dst], o1 = sOff[dst + 1];
    float ad = sLd[tid];
    float m = -3e38f;
    for (int e = o0; e < o1; ++e) m = fmaxf(m, lrelu(sLs[sSrc[e] * 4 + h] + ad));
    float dn = 0.f;
    for (int e = o0; e < o1; ++e){
      float ee = __expf(lrelu(sLs[sSrc[e] * 4 + h] + ad) - m);
      sW[h * 632 + e] = ee; dn += ee;
    }
    sDen[h * 211 + dst] = 1.0f / (dn + 1e-16f);
  }
  __syncthreads();

  // ---- P8: per head: y_h -> sY, MFMA accumulate ----
  f32x4 accO[4][2];
  #pragma unroll
  for (int s = 0; s < 4; ++s){ accO[s][0] = (f32x4){0,0,0,0}; accO[s][1] = (f32x4){0,0,0,0}; }
  #pragma unroll 1
  for (int h = 0; h < 4; ++h){
    const float* wp = sW + h * 632;
    for (int dst = wv; dst < NPG; dst += 16){
      int o0 = sOff[dst], o1 = sOff[dst + 1];
      float a0 = 0.f, a1 = 0.f;
      for (int e = o0; e < o1; ++e){
        int sn = sSrc[e];
        float w = wp[e];
        a0 += w * bf2f(sX[swz(sn, c0)]);
        a1 += w * bf2f(sX[swz(sn, c1)]);
      }
      float sc = 0.25f * sDen[h * 211 + dst];
      sY[swz(dst, c0)] = f2bf(a0 * sc);
      sY[swz(dst, c1)] = f2bf(a1 * sc);
    }
    __syncthreads();
    #pragma unroll
    for (int kk = 0; kk < 4; ++kk){
      int k0 = kk * 32 + (lg << 2);
      #pragma unroll
      for (int s = 0; s < 4; ++s) if (tact[s]){
        const u16* B0 = W2t + (size_t)(tcb[s] + l15) * 512 + h * 128 + k0;
        const u16* B1 = W2t + (size_t)(tcb[s] + 16 + l15) * 512 + h * 128 + k0;
        short8 bf0 = pack8(*(const ushort4*)B0, *(const ushort4*)(B0 + 16));
        short8 bf1 = pack8(*(const ushort4*)B1, *(const ushort4*)(B1 + 16));
        int rr = tmi[s] * 16 + l15; rr = rr < NPG ? rr : NPG - 1;
        short8 af = pack8(*(const ushort4*)&sY[swz(rr, k0)],
                          *(const ushort4*)&sY[swz(rr, k0 + 16)]);
        accO[s][0] = __builtin_amdgcn_mfma_f32_16x16x32_bf16(af, bf0, accO[s][0], 0, 0, 0);
        accO[s][1] = __builtin_amdgcn_mfma_f32_16x16x32_bf16(af, bf1, accO[s][1], 0, 0, 0);
      }
    }
    __syncthreads();
  }

  // ---- P9: out2 = relu(acc + b2) -> sX ----
  #pragma unroll
  for (int s = 0; s < 4; ++s) if (tact[s]){
    int r0 = tmi[s] * 16 + (lg << 2);
    #pragma unroll
    for (int ct = 0; ct < 2; ++ct){
      int col = tcb[s] + ct * 16 + l15;
      float bv = b2[col];
      #pragma unroll
      for (int r = 0; r < 4; ++r){
        int row = r0 + r;
        if (row < NPG) sX[swz(row, col)] = f2bf(fmaxf(accO[s][ct][r] + bv, 0.f));
      }
    }
  }
  __syncthreads();

  // ---- P10: final projections -> out (f32) ----
  if (tid < 203){
    float s; int pos;
    if (tid < 200){
      int row = 11 + tid;
      s = boff[0];
      #pragma unroll
      for (int j = 0; j < 32; ++j){
        ushort4 xv = *(const ushort4*)&sX[swz(row, j * 4)];
        #pragma unroll
        for (int t = 0; t < 4; ++t) s += bf2f(((const u16*)&xv)[t]) * Woff[j * 4 + t];
      }
      pos = 2 + tid;
    } else if (tid < 202){
      int j2 = tid - 200;
      s = bacc[j2];
      #pragma unroll
      for (int j = 0; j < 32; ++j){
        ushort4 xv = *(const ushort4*)&sX[swz(0, j * 4)];
        #pragma unroll
        for (int t = 0; t < 4; ++t) s += bf2f(((const u16*)&xv)[t]) * Wacc[(j * 4 + t) * 2 + j2];
      }
      float lm = logf(amask[b * 2 + j2]);
      s += fmaxf(lm, -3.402823466e38f);
      pos = j2;
    } else {
      s = bvf[0];
      #pragma unroll
      for (int j = 0; j < 32; ++j){
        ushort4 xv = *(const ushort4*)&sX[swz(0, j * 4)];
        #pragma unroll
        for (int t = 0; t < 4; ++t) s += bf2f(((const u16*)&xv)[t]) * Wvf[j * 4 + t];
      }
      pos = 202;
    }
    out[(size_t)b * 203 + pos] = s;
  }
}

extern "C" void kernel_launch(void* const* d_in, const int* in_sizes, int n_in,
                              void* d_out, int out_size, void* d_ws, size_t ws_size,
                              hipStream_t stream){
  (void)in_sizes; (void)n_in; (void)out_size; (void)ws_size;
  const float* head = (const float*)d_in[0];
  const float* obj  = (const float*)d_in[1];
  const float* val  = (const float*)d_in[2];
  const int*   eidx = (const int*)d_in[3];
  const float* amask= (const float*)d_in[4];
  const float* Wh   = (const float*)d_in[5];
  const float* bh   = (const float*)d_in[6];
  const float* Wo   = (const float*)d_in[7];
  const float* bo   = (const float*)d_in[8];
  const float* Wv   = (const float*)d_in[9];
  const float* bv   = (const float*)d_in[10];
  const float* W1   = (const float*)d_in[11];
  const float* as1  = (const float*)d_in[12];
  const float* ad1  = (const float*)d_in[13];
  const float* b1   = (const float*)d_in[14];
  const float* W2   = (const float*)d_in[15];
  const float* as2  = (const float*)d_in[16];
  const float* ad2  = (const float*)d_in[17];
  const float* b2   = (const float*)d_in[18];
  const float* Wacc = (const float*)d_in[19];
  const float* bacc = (const float*)d_in[20];
  const float* Woff = (const float*)d_in[21];
  const float* boff = (const float*)d_in[22];
  const float* Wvf  = (const float*)d_in[23];
  const float* bvf  = (const float*)d_in[24];
  float* out = (float*)d_out;

  char* ws = (char*)d_ws;
  u16*   W1t = (u16*)ws;                    //  32768 B
  u16*   W2t = (u16*)(ws + 32768);          // 131072 B
  float* wms = (float*)(ws + 163840);       //   2048 B
  float* wmd = (float*)(ws + 165888);       //   2048 B

  k_prept<<<320, 256, 0, stream>>>(W1, W2, W1t, W2t);
  k_prepwm<<<4, 256, 0, stream>>>(W2, as2, ad2, wms, wmd);
  k_graph<<<NB, 1024, 0, stream>>>(head, obj, val, eidx, amask,
                                   Wh, bh, Wo, bo, Wv, bv,
                                   W1t, as1, ad1, b1,
                                   W2t, wms, wmd, b2,
                                   Wacc, bacc, Woff, boff, Wvf, bvf, out);
}

// Round 6
// 243.659 us; speedup vs baseline: 1.9114x; 1.1465x over previous
//
#include <hip/hip_runtime.h>

typedef unsigned short u16;
typedef unsigned int u32;
typedef short short8 __attribute__((ext_vector_type(8)));
typedef float f32x4 __attribute__((ext_vector_type(4)));

#define NB   512
#define NPG  211
#define NOBJ 10
#define NVAL 200
#define NE   420
#define NN   (NB * NPG)

__device__ __forceinline__ float bf2f(u16 u){
  union { unsigned i; float f; } v; v.i = ((unsigned)u) << 16; return v.f;
}
__device__ __forceinline__ u16 f2bf(float f){
  union { float f; unsigned i; } v; v.f = f;
  return (u16)((v.i + 0x7FFFu + ((v.i >> 16) & 1u)) >> 16);
}
__device__ __forceinline__ float lo_bf(u32 u){ union{u32 i;float f;}v; v.i=u<<16; return v.f; }
__device__ __forceinline__ float hi_bf(u32 u){ union{u32 i;float f;}v; v.i=u&0xffff0000u; return v.f; }
__device__ __forceinline__ u32 pack_bf(float a, float b){ return (u32)f2bf(a) | ((u32)f2bf(b)<<16); }
__device__ __forceinline__ float lrelu(float s){ return s > 0.f ? s : 0.2f * s; }
__device__ __forceinline__ short8 pack8(ushort4 a, ushort4 b){
  short8 v;
  v[0]=(short)a.x; v[1]=(short)a.y; v[2]=(short)a.z; v[3]=(short)a.w;
  v[4]=(short)b.x; v[5]=(short)b.y; v[6]=(short)b.z; v[7]=(short)b.w;
  return v;
}
// XOR swizzle inside a [*][128] u16 LDS tile, 4-element chunk granularity.
__device__ __forceinline__ int swz(int r, int c){
  return (r << 7) + (((c & ~3) ^ ((r & 15) << 2)) | (c & 3));
}

// ---------------- prep: transposed weights, f32 -> bf16 (ws) ----------------
__global__ __launch_bounds__(256) void k_prept(const float* __restrict__ W1, const float* __restrict__ W2,
                                               u16* __restrict__ W1t, u16* __restrict__ W2t){
  int gid = blockIdx.x * 256 + threadIdx.x;      // 320 blocks -> 81920
  if (gid < 16384){
    int k = gid >> 7, n = gid & 127;
    W1t[n * 128 + k] = f2bf(W1[k * 128 + n]);
  } else {
    int t = gid - 16384;
    int n = t >> 9, kk = t & 511;
    int h = kk >> 7, c = kk & 127;
    W2t[n * 512 + kk] = f2bf(W2[c * 512 + h * 128 + n]);
  }
}

// ---------------- prep: layer-2 attention vectors (ws, f32) ----------------
__global__ __launch_bounds__(256) void k_prepwm(const float* __restrict__ W2, const float* __restrict__ as2,
                                                const float* __restrict__ ad2,
                                                float* __restrict__ wms, float* __restrict__ wmd){
  int gid = blockIdx.x * 256 + threadIdx.x;      // 4 blocks -> 1024
  int which = gid >> 9, hk = gid & 511;
  int h = hk >> 7, k = hk & 127;
  const float* av = which ? ad2 : as2;
  float s = 0.f;
  for (int j = 0; j < 128; ++j)
    s += W2[k * 512 + h * 128 + j] * av[h * 128 + j];
  (which ? wmd : wms)[hk] = s;
}

// ---------------- fully fused per-graph kernel (1024 threads) ----------------
// LDS map (bytes): same as R5; end 135004
__global__ __launch_bounds__(1024, 1) void k_graph(
    const float* __restrict__ head, const float* __restrict__ obj, const float* __restrict__ val,
    const int* __restrict__ eidx, const float* __restrict__ amask,
    const float* __restrict__ Wh, const float* __restrict__ bh,
    const float* __restrict__ Wo, const float* __restrict__ bo,
    const float* __restrict__ Wv, const float* __restrict__ bv,
    const u16* __restrict__ W1t, const float* __restrict__ as1, const float* __restrict__ ad1,
    const float* __restrict__ b1,
    const u16* __restrict__ W2t, const float* __restrict__ wms, const float* __restrict__ wmd,
    const float* __restrict__ b2,
    const float* __restrict__ Wacc, const float* __restrict__ bacc,
    const float* __restrict__ Woff, const float* __restrict__ boff,
    const float* __restrict__ Wvf,  const float* __restrict__ bvf,
    float* __restrict__ out)
{
  __shared__ __align__(16) char sm[135008];
  u16*   sX   = (u16*)sm;
  u16*   sY   = (u16*)(sm + 54016);
  float* sLs  = (float*)(sm + 108032);
  float* sLd  = (float*)(sm + 111408);
  float* sW   = (float*)(sm + 114784);
  float* sDen = (float*)(sm + 124896);
  int*   sEs  = (int*)(sm + 128272);
  int*   sEd  = (int*)(sm + 129952);
  int*   sOff = (int*)(sm + 131632);
  int*   sSrc = (int*)(sm + 132480);

  const int b    = blockIdx.x;
  const int tid  = threadIdx.x;
  const int lane = tid & 63;
  const int wv   = tid >> 6;          // 16 waves
  const int l15  = lane & 15;
  const int lg   = lane >> 4;
  // paired-column gather assignment: cols (2*lane, 2*lane+1)
  const int cp   = lane << 1;
  const int cHi  = cp & ~3, cLo = cp & 3;
  const int hh   = lane >> 4;         // head of the col pair (layer 1)

  // MFMA tile assignment: 14 row-tiles(16) x 4 col-pairs(32) = 56 tiles over 16 waves
  int tmi[4], tcb[4]; bool tact[4];
  #pragma unroll
  for (int s = 0; s < 4; ++s){
    int t = wv + (s << 4);
    tact[s] = t < 56; tmi[s] = t >> 2; tcb[s] = (t & 3) << 5;
  }

  // ---- P0: stage edges + att1 vectors ----
  const int* eg = eidx + (size_t)b * 2 * NE;
  if (tid < NE){ sEs[tid] = eg[tid]; sEd[tid] = eg[NE + tid]; }
  else if (tid >= 512 && tid < 640)      sDen[tid - 512] = as1[tid - 512];   // as1 -> sDen[0..127]
  else if (tid >= 640 && tid < 768)      sDen[tid - 512] = ad1[tid - 640];   // ad1 -> sDen[128..255]

  // ---- P1: embed -> sX (bf16) ----
  for (int it = tid; it < NPG * 32; it += 1024){
    int n = it >> 5, cc = (it & 31) << 2;
    float a[4];
    if (n == 0){
      const float* in = head + (size_t)b * 2;
      float i0 = in[0], i1 = in[1];
      #pragma unroll
      for (int t = 0; t < 4; ++t){ int c = cc + t; a[t] = bh[c] + i0 * Wh[c] + i1 * Wh[128 + c]; }
    } else if (n <= NOBJ){
      const float* in = obj + ((size_t)b * NOBJ + (n - 1)) * 2;
      float i0 = in[0], i1 = in[1];
      #pragma unroll
      for (int t = 0; t < 4; ++t){ int c = cc + t; a[t] = bo[c] + i0 * Wo[c] + i1 * Wo[128 + c]; }
    } else {
      const float* in = val + ((size_t)b * NVAL + (n - 11)) * 5;
      float f[5];
      #pragma unroll
      for (int k = 0; k < 5; ++k) f[k] = in[k];
      #pragma unroll
      for (int t = 0; t < 4; ++t){
        int c = cc + t; float s = bv[c];
        #pragma unroll
        for (int k = 0; k < 5; ++k) s += f[k] * Wv[k * 128 + c];
        a[t] = s;
      }
    }
    ushort4 u;
    u.x = f2bf(fmaxf(a[0], 0.f)); u.y = f2bf(fmaxf(a[1], 0.f));
    u.z = f2bf(fmaxf(a[2], 0.f)); u.w = f2bf(fmaxf(a[3], 0.f));
    *(ushort4*)&sX[swz(n, cc)] = u;
  }
  __syncthreads();

  // ---- P2a: degrees (vectorized int4 scan over edges) ----
  if (tid < NPG){
    int c = 1;
    const int4* p4 = (const int4*)sEd;
    #pragma unroll 4
    for (int i = 0; i < NE / 4; ++i){
      int4 v = p4[i];
      c += (v.x == tid) + (v.y == tid) + (v.z == tid) + (v.w == tid);
    }
    sOff[tid] = c;
  }
  __syncthreads();
  // ---- P2b: Hillis-Steele exclusive scan (256 lanes, sSrc as temp) ----
  {
    int deg = (tid < NPG) ? sOff[tid] : 0;
    int v = deg;
    #pragma unroll
    for (int st = 1; st < 256; st <<= 1){
      if (tid < 256) sSrc[tid] = v;
      __syncthreads();
      if (tid < 256 && tid >= st) v += sSrc[tid - st];
      __syncthreads();
    }
    if (tid < NPG) sOff[tid] = v - deg;
    if (tid == NPG - 1) sOff[NPG] = v;
  }
  __syncthreads();
  // ---- P2c: deterministic CSR fill (vectorized reads) ----
  if (tid < NPG){
    int p = sOff[tid];
    sSrc[p++] = tid;                              // self loop first
    const int4* pd4 = (const int4*)sEd;
    const int4* ps4 = (const int4*)sEs;
    for (int i = 0; i < NE / 4; ++i){
      int4 d = pd4[i]; int4 s = ps4[i];
      if (d.x == tid) sSrc[p++] = s.x;
      if (d.y == tid) sSrc[p++] = s.y;
      if (d.z == tid) sSrc[p++] = s.z;
      if (d.w == tid) sSrc[p++] = s.w;
    }
  }
  __syncthreads();

  // ---- P4: gemm1  xs1 = x @ W1 -> sY ----
  {
    f32x4 acc[4][2];
    #pragma unroll
    for (int s = 0; s < 4; ++s){ acc[s][0] = (f32x4){0,0,0,0}; acc[s][1] = (f32x4){0,0,0,0}; }
    #pragma unroll
    for (int kk = 0; kk < 4; ++kk){
      int k0 = kk * 32 + (lg << 2);
      #pragma unroll
      for (int s = 0; s < 4; ++s) if (tact[s]){
        const u16* B0 = W1t + (size_t)(tcb[s] + l15) * 128 + k0;
        const u16* B1 = W1t + (size_t)(tcb[s] + 16 + l15) * 128 + k0;
        short8 bf0 = pack8(*(const ushort4*)B0, *(const ushort4*)(B0 + 16));
        short8 bf1 = pack8(*(const ushort4*)B1, *(const ushort4*)(B1 + 16));
        int rr = tmi[s] * 16 + l15; rr = rr < NPG ? rr : NPG - 1;
        short8 af = pack8(*(const ushort4*)&sX[swz(rr, k0)],
                          *(const ushort4*)&sX[swz(rr, k0 + 16)]);
        acc[s][0] = __builtin_amdgcn_mfma_f32_16x16x32_bf16(af, bf0, acc[s][0], 0, 0, 0);
        acc[s][1] = __builtin_amdgcn_mfma_f32_16x16x32_bf16(af, bf1, acc[s][1], 0, 0, 0);
      }
    }
    #pragma unroll
    for (int s = 0; s < 4; ++s) if (tact[s]){
      int r0 = tmi[s] * 16 + (lg << 2);
      #pragma unroll
      for (int ct = 0; ct < 2; ++ct){
        int col = tcb[s] + ct * 16 + l15;
        #pragma unroll
        for (int r = 0; r < 4; ++r){
          int row = r0 + r;
          if (row < NPG) sY[swz(row, col)] = f2bf(acc[s][ct][r]);
        }
      }
    }
  }
  __syncthreads();

  // ---- P5: att1 logits (att vectors staged in sDen[0..255]) ----
  if (tid < NPG * 4){
    int n = tid >> 2, h = tid & 3;
    float s = 0.f, d = 0.f;
    #pragma unroll
    for (int j = 0; j < 8; ++j){
      int c = h * 32 + j * 4;
      ushort4 xv = *(const ushort4*)&sY[swz(n, c)];
      #pragma unroll
      for (int t = 0; t < 4; ++t){
        float xf = bf2f(((const u16*)&xv)[t]);
        s += xf * sDen[c + t];
        d += xf * sDen[128 + c + t];
      }
    }
    sLs[tid] = s; sLd[tid] = d;
  }
  __syncthreads();

  // ---- P5b: layer-1 per-slot softmax weights (chunk-4 prefetch) ----
  if (tid < NPG * 4){
    int dst = tid >> 2, h = tid & 3;
    int o0 = sOff[dst], o1 = sOff[dst + 1];
    float ad = sLd[tid];
    float m = -3e38f;
    int e = o0;
    for (; e + 4 <= o1; e += 4){
      int s0 = sSrc[e], s1 = sSrc[e+1], s2 = sSrc[e+2], s3 = sSrc[e+3];
      float l0 = sLs[s0*4+h], l1 = sLs[s1*4+h], l2 = sLs[s2*4+h], l3 = sLs[s3*4+h];
      m = fmaxf(m, fmaxf(fmaxf(lrelu(l0+ad), lrelu(l1+ad)), fmaxf(lrelu(l2+ad), lrelu(l3+ad))));
    }
    for (; e < o1; ++e) m = fmaxf(m, lrelu(sLs[sSrc[e]*4+h] + ad));
    float dn = 0.f;
    e = o0;
    for (; e + 4 <= o1; e += 4){
      int s0 = sSrc[e], s1 = sSrc[e+1], s2 = sSrc[e+2], s3 = sSrc[e+3];
      float e0 = __expf(lrelu(sLs[s0*4+h]+ad) - m);
      float e1 = __expf(lrelu(sLs[s1*4+h]+ad) - m);
      float e2 = __expf(lrelu(sLs[s2*4+h]+ad) - m);
      float e3 = __expf(lrelu(sLs[s3*4+h]+ad) - m);
      sW[h*632+e] = e0; sW[h*632+e+1] = e1; sW[h*632+e+2] = e2; sW[h*632+e+3] = e3;
      dn += (e0 + e1) + (e2 + e3);
    }
    for (; e < o1; ++e){
      float ee = __expf(lrelu(sLs[sSrc[e]*4+h]+ad) - m);
      sW[h*632+e] = ee; dn += ee;
    }
    sDen[h * 211 + dst] = 1.0f / (dn + 1e-16f);
  }
  __syncthreads();

  // ---- P6: gat1 aggregation -> x1 into sX (paired cols, b32 loads) ----
  {
    const float b1v0 = b1[cp], b1v1 = b1[cp + 1];
    const float* wp  = sW + hh * 632;
    const float* dnp = sDen + hh * 211;
    for (int dst = wv; dst < NPG; dst += 16){
      int o0 = sOff[dst], o1 = sOff[dst + 1];
      float a0 = 0.f, a1 = 0.f;
      int e = o0;
      for (; e + 4 <= o1; e += 4){
        int s0 = sSrc[e], s1 = sSrc[e+1], s2 = sSrc[e+2], s3 = sSrc[e+3];
        u32 f0 = *(const u32*)&sY[(s0<<7) + (cHi ^ ((s0&15)<<2)) + cLo];
        u32 f1 = *(const u32*)&sY[(s1<<7) + (cHi ^ ((s1&15)<<2)) + cLo];
        u32 f2 = *(const u32*)&sY[(s2<<7) + (cHi ^ ((s2&15)<<2)) + cLo];
        u32 f3 = *(const u32*)&sY[(s3<<7) + (cHi ^ ((s3&15)<<2)) + cLo];
        float w0 = wp[e], w1 = wp[e+1], w2 = wp[e+2], w3 = wp[e+3];
        a0 += w0*lo_bf(f0) + w1*lo_bf(f1) + w2*lo_bf(f2) + w3*lo_bf(f3);
        a1 += w0*hi_bf(f0) + w1*hi_bf(f1) + w2*hi_bf(f2) + w3*hi_bf(f3);
      }
      for (; e < o1; ++e){
        int sn = sSrc[e];
        u32 f = *(const u32*)&sY[(sn<<7) + (cHi ^ ((sn&15)<<2)) + cLo];
        float w = wp[e];
        a0 += w * lo_bf(f); a1 += w * hi_bf(f);
      }
      float r = dnp[dst];
      *(u32*)&sX[(dst<<7) + (cHi ^ ((dst&15)<<2)) + cLo] =
        pack_bf(fmaxf(a0 * r + b1v0, 0.f), fmaxf(a1 * r + b1v1, 0.f));
    }
  }
  __syncthreads();

  // ---- P7a: stage wms/wmd into sW[0..1023] ----
  sW[tid] = (tid < 512) ? wms[tid] : wmd[tid - 512];
  __syncthreads();

  // ---- P7: att2 logits from x1 ----
  if (tid < NPG * 4){
    int n = tid >> 2, h = tid & 3;
    const float* wsp = sW + h * 128;
    const float* wdp = sW + 512 + h * 128;
    float s = 0.f, d = 0.f;
    #pragma unroll
    for (int j = 0; j < 32; ++j){
      ushort4 xv = *(const ushort4*)&sX[swz(n, j * 4)];
      #pragma unroll
      for (int t = 0; t < 4; ++t){
        float xf = bf2f(((const u16*)&xv)[t]);
        s += xf * wsp[j * 4 + t];
        d += xf * wdp[j * 4 + t];
      }
    }
    sLs[tid] = s; sLd[tid] = d;
  }
  __syncthreads();

  // ---- P7b: layer-2 per-slot softmax weights (chunk-4 prefetch) ----
  if (tid < NPG * 4){
    int dst = tid >> 2, h = tid & 3;
    int o0 = sOff[dst], o1 = sOff[dst + 1];
    float ad = sLd[tid];
    float m = -3e38f;
    int e = o0;
    for (; e + 4 <= o1; e += 4){
      int s0 = sSrc[e], s1 = sSrc[e+1], s2 = sSrc[e+2], s3 = sSrc[e+3];
      float l0 = sLs[s0*4+h], l1 = sLs[s1*4+h], l2 = sLs[s2*4+h], l3 = sLs[s3*4+h];
      m = fmaxf(m, fmaxf(fmaxf(lrelu(l0+ad), lrelu(l1+ad)), fmaxf(lrelu(l2+ad), lrelu(l3+ad))));
    }
    for (; e < o1; ++e) m = fmaxf(m, lrelu(sLs[sSrc[e]*4+h] + ad));
    float dn = 0.f;
    e = o0;
    for (; e + 4 <= o1; e += 4){
      int s0 = sSrc[e], s1 = sSrc[e+1], s2 = sSrc[e+2], s3 = sSrc[e+3];
      float e0 = __expf(lrelu(sLs[s0*4+h]+ad) - m);
      float e1 = __expf(lrelu(sLs[s1*4+h]+ad) - m);
      float e2 = __expf(lrelu(sLs[s2*4+h]+ad) - m);
      float e3 = __expf(lrelu(sLs[s3*4+h]+ad) - m);
      sW[h*632+e] = e0; sW[h*632+e+1] = e1; sW[h*632+e+2] = e2; sW[h*632+e+3] = e3;
      dn += (e0 + e1) + (e2 + e3);
    }
    for (; e < o1; ++e){
      float ee = __expf(lrelu(sLs[sSrc[e]*4+h]+ad) - m);
      sW[h*632+e] = ee; dn += ee;
    }
    sDen[h * 211 + dst] = 1.0f / (dn + 1e-16f);
  }
  __syncthreads();

  // ---- P8: per head: y_h -> sY (paired cols), MFMA accumulate ----
  f32x4 accO[4][2];
  #pragma unroll
  for (int s = 0; s < 4; ++s){ accO[s][0] = (f32x4){0,0,0,0}; accO[s][1] = (f32x4){0,0,0,0}; }
  #pragma unroll 1
  for (int h = 0; h < 4; ++h){
    const float* wp = sW + h * 632;
    for (int dst = wv; dst < NPG; dst += 16){
      int o0 = sOff[dst], o1 = sOff[dst + 1];
      float a0 = 0.f, a1 = 0.f;
      int e = o0;
      for (; e + 4 <= o1; e += 4){
        int s0 = sSrc[e], s1 = sSrc[e+1], s2 = sSrc[e+2], s3 = sSrc[e+3];
        u32 f0 = *(const u32*)&sX[(s0<<7) + (cHi ^ ((s0&15)<<2)) + cLo];
        u32 f1 = *(const u32*)&sX[(s1<<7) + (cHi ^ ((s1&15)<<2)) + cLo];
        u32 f2 = *(const u32*)&sX[(s2<<7) + (cHi ^ ((s2&15)<<2)) + cLo];
        u32 f3 = *(const u32*)&sX[(s3<<7) + (cHi ^ ((s3&15)<<2)) + cLo];
        float w0 = wp[e], w1 = wp[e+1], w2 = wp[e+2], w3 = wp[e+3];
        a0 += w0*lo_bf(f0) + w1*lo_bf(f1) + w2*lo_bf(f2) + w3*lo_bf(f3);
        a1 += w0*hi_bf(f0) + w1*hi_bf(f1) + w2*hi_bf(f2) + w3*hi_bf(f3);
      }
      for (; e < o1; ++e){
        int sn = sSrc[e];
        u32 f = *(const u32*)&sX[(sn<<7) + (cHi ^ ((sn&15)<<2)) + cLo];
        float w = wp[e];
        a0 += w * lo_bf(f); a1 += w * hi_bf(f);
      }
      float sc = 0.25f * sDen[h * 211 + dst];
      *(u32*)&sY[(dst<<7) + (cHi ^ ((dst&15)<<2)) + cLo] = pack_bf(a0 * sc, a1 * sc);
    }
    __syncthreads();
    #pragma unroll
    for (int kk = 0; kk < 4; ++kk){
      int k0 = kk * 32 + (lg << 2);
      #pragma unroll
      for (int s = 0; s < 4; ++s) if (tact[s]){
        const u16* B0 = W2t + (size_t)(tcb[s] + l15) * 512 + h * 128 + k0;
        const u16* B1 = W2t + (size_t)(tcb[s] + 16 + l15) * 512 + h * 128 + k0;
        short8 bf0 = pack8(*(const ushort4*)B0, *(const ushort4*)(B0 + 16));
        short8 bf1 = pack8(*(const ushort4*)B1, *(const ushort4*)(B1 + 16));
        int rr = tmi[s] * 16 + l15; rr = rr < NPG ? rr : NPG - 1;
        short8 af = pack8(*(const ushort4*)&sY[swz(rr, k0)],
                          *(const ushort4*)&sY[swz(rr, k0 + 16)]);
        accO[s][0] = __builtin_amdgcn_mfma_f32_16x16x32_bf16(af, bf0, accO[s][0], 0, 0, 0);
        accO[s][1] = __builtin_amdgcn_mfma_f32_16x16x32_bf16(af, bf1, accO[s][1], 0, 0, 0);
      }
    }
    __syncthreads();
  }

  // ---- P9: out2 = relu(acc + b2) -> sX ----
  #pragma unroll
  for (int s = 0; s < 4; ++s) if (tact[s]){
    int r0 = tmi[s] * 16 + (lg << 2);
    #pragma unroll
    for (int ct = 0; ct < 2; ++ct){
      int col = tcb[s] + ct * 16 + l15;
      float bv = b2[col];
      #pragma unroll
      for (int r = 0; r < 4; ++r){
        int row = r0 + r;
        if (row < NPG) sX[swz(row, col)] = f2bf(fmaxf(accO[s][ct][r] + bv, 0.f));
      }
    }
  }
  __syncthreads();

  // ---- P10: final projections -> out (f32), 4 threads per output ----
  if (tid < 812){
    int o = tid >> 2, q = tid & 3;
    float s = 0.f;
    if (o < 200){
      int row = 11 + o;
      #pragma unroll
      for (int j = 0; j < 8; ++j){
        int c = q * 32 + j * 4;
        ushort4 xv = *(const ushort4*)&sX[swz(row, c)];
        s += bf2f(xv.x)*Woff[c] + bf2f(xv.y)*Woff[c+1] + bf2f(xv.z)*Woff[c+2] + bf2f(xv.w)*Woff[c+3];
      }
    } else if (o < 202){
      int j2 = o - 200;
      #pragma unroll
      for (int j = 0; j < 8; ++j){
        int c = q * 32 + j * 4;
        ushort4 xv = *(const ushort4*)&sX[swz(0, c)];
        s += bf2f(xv.x)*Wacc[c*2+j2] + bf2f(xv.y)*Wacc[(c+1)*2+j2]
           + bf2f(xv.z)*Wacc[(c+2)*2+j2] + bf2f(xv.w)*Wacc[(c+3)*2+j2];
      }
    } else {
      #pragma unroll
      for (int j = 0; j < 8; ++j){
        int c = q * 32 + j * 4;
        ushort4 xv = *(const ushort4*)&sX[swz(0, c)];
        s += bf2f(xv.x)*Wvf[c] + bf2f(xv.y)*Wvf[c+1] + bf2f(xv.z)*Wvf[c+2] + bf2f(xv.w)*Wvf[c+3];
      }
    }
    s += __shfl_xor(s, 1);
    s += __shfl_xor(s, 2);
    if (q == 0){
      if (o < 200){
        out[(size_t)b * 203 + 2 + o] = s + boff[0];
      } else if (o < 202){
        int j2 = o - 200;
        float lm = logf(amask[b * 2 + j2]);
        out[(size_t)b * 203 + j2] = s + bacc[j2] + fmaxf(lm, -3.402823466e38f);
      } else {
        out[(size_t)b * 203 + 202] = s + bvf[0];
      }
    }
  }
}

extern "C" void kernel_launch(void* const* d_in, const int* in_sizes, int n_in,
                              void* d_out, int out_size, void* d_ws, size_t ws_size,
                              hipStream_t stream){
  (void)in_sizes; (void)n_in; (void)out_size; (void)ws_size;
  const float* head = (const float*)d_in[0];
  const float* obj  = (const float*)d_in[1];
  const float* val  = (const float*)d_in[2];
  const int*   eidx = (const int*)d_in[3];
  const float* amask= (const float*)d_in[4];
  const float* Wh   = (const float*)d_in[5];
  const float* bh   = (const float*)d_in[6];
  const float* Wo   = (const float*)d_in[7];
  const float* bo   = (const float*)d_in[8];
  const float* Wv   = (const float*)d_in[9];
  const float* bv   = (const float*)d_in[10];
  const float* W1   = (const float*)d_in[11];
  const float* as1  = (const float*)d_in[12];
  const float* ad1  = (const float*)d_in[13];
  const float* b1   = (const float*)d_in[14];
  const float* W2   = (const float*)d_in[15];
  const float* as2  = (const float*)d_in[16];
  const float* ad2  = (const float*)d_in[17];
  const float* b2   = (const float*)d_in[18];
  const float* Wacc = (const float*)d_in[19];
  const float* bacc = (const float*)d_in[20];
  const float* Woff = (const float*)d_in[21];
  const float* boff = (const float*)d_in[22];
  const float* Wvf  = (const float*)d_in[23];
  const float* bvf  = (const float*)d_in[24];
  float* out = (float*)d_out;

  char* ws = (char*)d_ws;
  u16*   W1t = (u16*)ws;                    //  32768 B
  u16*   W2t = (u16*)(ws + 32768);          // 131072 B
  float* wms = (float*)(ws + 163840);       //   2048 B
  float* wmd = (float*)(ws + 165888);       //   2048 B

  k_prept<<<320, 256, 0, stream>>>(W1, W2, W1t, W2t);
  k_prepwm<<<4, 256, 0, stream>>>(W2, as2, ad2, wms, wmd);
  k_graph<<<NB, 1024, 0, stream>>>(head, obj, val, eidx, amask,
                                   Wh, bh, Wo, bo, Wv, bv,
                                   W1t, as1, ad1, b1,
                                   W2t, wms, wmd, b2,
                                   Wacc, bacc, Woff, boff, Wvf, bvf, out);
}